// Round 1
// baseline (306.732 us; speedup 1.0000x reference)
//
#include <hip/hip_runtime.h>
#include <math.h>

// Problem constants (match reference):
//   D_M = 1024, VOCAB = 50257, BASE = 10000.0, B = 8, S = 4096
// out[b,s,d] = emb_table[x[b,s], d] + pe[s,d]
//   pe[s, 2i]   = sin(s * base^(-2i/D))
//   pe[s, 2i+1] = cos(s * base^(-2i/D))
//
// Restructure vs previous version: ONE BLOCK PER POSITION s (4096 blocks),
// looping over the B=8 batch rows that share pe[s, :]. This computes the
// expensive large-argument sincosf pair ONCE per (s, column-pair) instead of
// 8x, turning a VALU-bound kernel (~14% HBM BW) into a memory-bound one.
// PE math is bit-identical to the previous passing kernel (same exp2f/sincosf),
// so absmax is unchanged.

#define D_M  1024
#define SEQ  4096
#define NB   8

__global__ __launch_bounds__(256) void SinusoidalEmbedding_83030307766274_kernel(
    const int* __restrict__ x,
    const float* __restrict__ emb_table,
    float* __restrict__ out)
{
    const int s  = blockIdx.x;          // sequence position in [0, SEQ)
    const int d4 = threadIdx.x;         // float4 index within row, [0, 256)

    // ---- 1) Gather the 8 token rows for this position (block-uniform ids) ----
    int rows[NB];
#pragma unroll
    for (int b = 0; b < NB; ++b)
        rows[b] = x[b * SEQ + s];       // wave-uniform -> scalar loads

    // Issue all 8 independent float4 gathers up front so their latency
    // overlaps the transcendental computation below.
    float4 v[NB];
#pragma unroll
    for (int b = 0; b < NB; ++b) {
        const float4* __restrict__ src =
            (const float4*)(emb_table + (size_t)rows[b] * D_M);
        v[b] = src[d4];
    }

    // ---- 2) PE row for this s, columns 4*d4 .. 4*d4+3 (pairs i0, i0+1) ----
    // inv_freq(i) = 10000^(-2i/D) = exp2(i * c), c = -2*log2(10000)/D
    const float c  = -2.0f * 13.28771237954945f / (float)D_M;
    const float i0 = (float)(2 * d4);
    const float f0 = exp2f(i0 * c);
    const float f1 = exp2f((i0 + 1.0f) * c);
    const float sp = (float)s;

    float s0, c0, s1, c1;
    sincosf(sp * f0, &s0, &c0);
    sincosf(sp * f1, &s1, &c1);

    // ---- 3) Add + store the 8 output rows ----
    const size_t out_d4 = (size_t)d4;
#pragma unroll
    for (int b = 0; b < NB; ++b) {
        float4 o = v[b];
        o.x += s0;   // even col: sin
        o.y += c0;   // odd  col: cos
        o.z += s1;
        o.w += c1;
        ((float4*)out)[((size_t)b * SEQ + s) * (D_M / 4) + out_d4] = o;
    }
}

extern "C" void kernel_launch(void* const* d_in, const int* in_sizes, int n_in,
                              void* d_out, int out_size, void* d_ws, size_t ws_size,
                              hipStream_t stream)
{
    const int*   x         = (const int*)d_in[0];     // [B, S] token ids
    const float* emb_table = (const float*)d_in[1];   // [VOCAB, D_M] fp32
    float*       out       = (float*)d_out;           // [B, S, D_M] fp32

    // One block per sequence position; each block handles all B=8 batches.
    SinusoidalEmbedding_83030307766274_kernel<<<SEQ, 256, 0, stream>>>(x, emb_table, out);
}